// Round 1
// baseline (152.226 us; speedup 1.0000x reference)
//
#include <hip/hip_runtime.h>
#include <math.h>

#define MM 64
#define NA 24
#define NP 276
#define NT 6000
#define QC 0.22360679774997896f
#define EXPC 0.01666666666666667f  // 5/(3*sig^2), sig=10

// ---- workspace layout (float offsets) ----
// wT[t][m] 6048*64, eT[t][m] 6048*64 (rows 6000..6047 zeroed by k1 block 374)
// slab[cid][mat][p][m]: 28*2*276*64 partials from k2 (no atomics)
// esP[tile][m], swP[tile][m]: 375*64 partials from k1 (no atomics)
#define OFF_WT   0
#define OFF_ET   387072
#define OFF_SLAB 774144
#define OFF_ESP  1763328
#define OFF_SWP  1787328

// k1 tiles
#define G1_BS 280  // float2 per t-row
#define G1_AS 36   // As row stride (floats)
// k2 tiles
#define G2S   28   // k-chunks (18*28 = 504 blocks = 2/CU, uniform)
#define G2CH  216  // k per chunk
#define G2R   72   // k per LDS staging round (3 rounds/chunk)
#define G2_AS 68
#define G2_BS 18

__device__ __forceinline__ void p2ij(int p, int& i, int& j) {
  int ii = (int)((1.0f + sqrtf(1.0f + 8.0f * (float)p)) * 0.5f);
  while (ii * (ii - 1) / 2 > p) ii--;
  while ((ii + 1) * ii / 2 <= p) ii++;
  j = p - ii * (ii - 1) / 2;
  i = ii;
}

// ---------- kernel 1: fused xs + stats + GEMM1 + elementwise ----------
// grid (375 t-tiles, 2 m-halves); block 256 = tile 32m x 16t.
// Thread: r = tid&15 -> m-pair (m0+2r, +1); c = tid>>4 -> t = t0+c.
// No atomics: per-block Es/sw partials stored to esP/swP[tile][m].
__global__ __launch_bounds__(256, 2) void k1(const float* __restrict__ Rs,
                                             const float* __restrict__ xt,
                                             const float* __restrict__ Ja,
                                             float* __restrict__ ws) {
  __shared__ __align__(16) float2 Bs[16][G1_BS];
  __shared__ __align__(16) float As[NP][G1_AS];
  __shared__ float sUUp[8][32];
  __shared__ float sUU[32];
  __shared__ float sVV[16], sC1[16];
  __shared__ float sEsW[4][32], sSwW[4][32];
  const int tid = threadIdx.x;
  const int t0 = blockIdx.x * 16;
  const int m0 = blockIdx.y * 32;

  // tail rows 6000..6047 of wT/eT zeroed once (consumed zero-padded by k2)
  if (blockIdx.x == 374) {
    float* tz = ws + (blockIdx.y ? OFF_ET : OFF_WT) + (size_t)NT * 64;
    for (int z = tid; z < 48 * 64; z += 256) tz[z] = 0.f;
  }

  // stage B: 16 t-rows x 69 float4-quads of xt & Ja, interleaved (v,j)
  for (int idx = tid; idx < 16 * 69; idx += 256) {
    const int row = idx / 69;
    const int kq = (idx - row * 69) * 4;
    const float4 v = *(const float4*)(xt + (size_t)(t0 + row) * NP + kq);
    const float4 j = *(const float4*)(Ja + (size_t)(t0 + row) * NP + kq);
    *(float4*)&Bs[row][kq]     = make_float4(v.x, j.x, v.y, j.y);
    *(float4*)&Bs[row][kq + 2] = make_float4(v.z, j.z, v.w, j.w);
  }
  // compute As[p][mloc] = xs directly from Rs (L1/L2-hot) + uu partials
  {
    const float* Rm = Rs + (size_t)m0 * NA * 3;
    float up = 0.f;
    for (int idx = tid; idx < NP * 32; idx += 256) {
      const int p = idx >> 5;
      const int ml = idx & 31;    // invariant per thread (stride 256)
      int i, j;
      p2ij(p, i, j);
      const float* ri = Rm + ml * 72 + i * 3;
      const float* rj = Rm + ml * 72 + j * 3;
      const float dx = ri[0] - rj[0];
      const float dy = ri[1] - rj[1];
      const float dz = ri[2] - rj[2];
      const float u = 1.0f / sqrtf(dx * dx + dy * dy + dz * dz);
      As[p][ml] = u;
      up = fmaf(u, u, up);
    }
    sUUp[tid >> 5][tid & 31] = up;
  }
  __syncthreads();

  // in-block stats: vv[t], c1[t] from staged Bs
  {
    const int tl = tid >> 4;
    const int l16 = tid & 15;
    float a = 0.f, b = 0.f;
    for (int k = l16; k < NP; k += 16) {
      const float2 x = Bs[tl][k];
      a = fmaf(x.x, x.x, a);
      b = fmaf(x.x, x.y, b);
    }
#pragma unroll
    for (int off = 8; off; off >>= 1) {
      a += __shfl_down(a, off, 16);
      b += __shfl_down(b, off, 16);
    }
    if (l16 == 0) { sVV[tl] = a; sC1[tl] = b; }
  }
  // reduce uu over the 8 p-chunks
  if (tid < 32) {
    float a = 0.f;
#pragma unroll
    for (int k = 0; k < 8; k++) a += sUUp[k][tid];
    sUU[tid] = a;
  }
  __syncthreads();

  const int r = tid & 15;   // m-pair
  const int c = tid >> 4;   // t-column
  const float2 uu2 = *(const float2*)&sUU[2 * r];

  float av0 = 0.f, av1 = 0.f, aj0 = 0.f, aj1 = 0.f;
#pragma unroll 4
  for (int kk = 0; kk < NP; kk += 2) {
    const float4 b  = *(const float4*)&Bs[c][kk];    // (v_k, j_k, v_k1, j_k1)
    const float2 a0 = *(const float2*)&As[kk][2 * r];
    const float2 a1 = *(const float2*)&As[kk + 1][2 * r];
    av0 = fmaf(a0.x, b.x, av0); aj0 = fmaf(a0.x, b.y, aj0);
    av1 = fmaf(a0.y, b.x, av1); aj1 = fmaf(a0.y, b.y, aj1);
    av0 = fmaf(a1.x, b.z, av0); aj0 = fmaf(a1.x, b.w, aj0);
    av1 = fmaf(a1.y, b.z, av1); aj1 = fmaf(a1.y, b.w, aj1);
  }

  // elementwise epilogue: t = t0+c, m = m0+2r+{0,1}
  const float vvt = sVV[c];
  const float c1t = sC1[c];
  float es2[2], sw2[2], wv[2], ev[2];
#pragma unroll
  for (int i = 0; i < 2; i++) {
    const float g1v = i ? av1 : av0;
    const float g2v = i ? aj1 : aj0;
    const float uum = i ? uu2.y : uu2.x;
    float d2 = fmaxf(uum - 2.f * g1v + vvt, 0.f);
    float xd = QC * sqrtf(d2);
    float dv = QC * (g2v - c1t);
    float ex = EXPC * __expf(-xd);
    float e1v = ex * (1.f + xd);
    float w_ = ex * dv;
    wv[i] = w_; ev[i] = e1v;
    es2[i] = e1v * dv;
    sw2[i] = w_;
  }
  const int t = t0 + c;
  *(float2*)(ws + OFF_WT + (size_t)t * 64 + m0 + 2 * r) = make_float2(wv[0], wv[1]);
  *(float2*)(ws + OFF_ET + (size_t)t * 64 + m0 + 2 * r) = make_float2(ev[0], ev[1]);

  // reduce es/sw over the wave's 4 c-groups, park per wave, plain stores
#pragma unroll
  for (int i = 0; i < 2; i++) {
    es2[i] += __shfl_down(es2[i], 32); es2[i] += __shfl_down(es2[i], 16);
    sw2[i] += __shfl_down(sw2[i], 32); sw2[i] += __shfl_down(sw2[i], 16);
  }
  const int w = tid >> 6;
  if ((tid & 63) < 16) {
    sEsW[w][2 * r + 0] = es2[0]; sEsW[w][2 * r + 1] = es2[1];
    sSwW[w][2 * r + 0] = sw2[0]; sSwW[w][2 * r + 1] = sw2[1];
  }
  __syncthreads();
  if (tid < 32) {
    const float es = sEsW[0][tid] + sEsW[1][tid] + sEsW[2][tid] + sEsW[3][tid];
    const float sw = sSwW[0][tid] + sSwW[1][tid] + sSwW[2][tid] + sSwW[3][tid];
    ws[OFF_ESP + (size_t)blockIdx.x * 64 + m0 + tid] = es;
    ws[OFF_SWP + (size_t)blockIdx.x * 64 + m0 + tid] = sw;
  }
}

// ---------- kernel 2: GEMM2 partials, no atomics ----------
// grid (18 p-tiles x 28 k-chunks of 216); block 256 = tile 64m x 16p.
// Thread: r = tid&31 -> m-pair (2r, 2r+1); c = tid>>5 -> p-pair (p0+2c, +1).
// Each block accumulates its full chunk in regs (3 LDS rounds of 72 k),
// then writes a private slab partial with plain stores.
__global__ __launch_bounds__(256, 2) void k2(const float* __restrict__ xt,
                                             const float* __restrict__ Ja,
                                             float* __restrict__ ws) {
  __shared__ __align__(16) float Aw[G2R][G2_AS];
  __shared__ __align__(16) float Ae[G2R][G2_AS];
  __shared__ __align__(16) float2 Bvj[G2R][G2_BS];
  const int tid = threadIdx.x;
  const int p0 = blockIdx.x * 16;
  const int cid = blockIdx.y;
  const int validp = (NP - p0 < 16) ? (NP - p0) : 16;
  const int r = tid & 31;
  const int c = tid >> 5;
  float f1[2][2] = {{0.f, 0.f}, {0.f, 0.f}};  // [m][p]
  float f2[2][2] = {{0.f, 0.f}, {0.f, 0.f}};

  for (int rnd = 0; rnd < 3; rnd++) {
    const int k0 = cid * G2CH + rnd * G2R;
    __syncthreads();
    for (int idx = tid; idx < G2R * 16; idx += 256) {
      const int k = idx >> 4;
      const int mq = (idx & 15) * 4;
      *(float4*)&Aw[k][mq] = *(const float4*)(ws + OFF_WT + (size_t)(k0 + k) * 64 + mq);
      *(float4*)&Ae[k][mq] = *(const float4*)(ws + OFF_ET + (size_t)(k0 + k) * 64 + mq);
    }
    for (int idx = tid; idx < G2R * 4; idx += 256) {
      const int k = idx >> 2;
      const int pq = (idx & 3) * 4;
      const int t = k0 + k;
      float4 v = make_float4(0.f, 0.f, 0.f, 0.f), j = v;
      if (pq < validp && t < NT) {
        v = *(const float4*)(xt + (size_t)t * NP + p0 + pq);
        j = *(const float4*)(Ja + (size_t)t * NP + p0 + pq);
      }
      *(float4*)&Bvj[k][pq]     = make_float4(v.x, j.x, v.y, j.y);
      *(float4*)&Bvj[k][pq + 2] = make_float4(v.z, j.z, v.w, j.w);
    }
    __syncthreads();
#pragma unroll 4
    for (int k = 0; k < G2R; k++) {
      const float2 aw = *(const float2*)&Aw[k][2 * r];
      const float2 ae = *(const float2*)&Ae[k][2 * r];
      const float4 b  = *(const float4*)&Bvj[k][2 * c];  // (v_p, j_p, v_p1, j_p1)
      f1[0][0] = fmaf(aw.x, b.x, f1[0][0]); f1[0][1] = fmaf(aw.x, b.z, f1[0][1]);
      f1[1][0] = fmaf(aw.y, b.x, f1[1][0]); f1[1][1] = fmaf(aw.y, b.z, f1[1][1]);
      f2[0][0] = fmaf(ae.x, b.y, f2[0][0]); f2[0][1] = fmaf(ae.x, b.w, f2[0][1]);
      f2[1][0] = fmaf(ae.y, b.y, f2[1][0]); f2[1][1] = fmaf(ae.y, b.w, f2[1][1]);
    }
  }

#pragma unroll
  for (int j = 0; j < 2; j++) {
    const int pl = 2 * c + j;
    if (pl < validp) {
      const int p = p0 + pl;
      float* b1 = ws + OFF_SLAB + ((size_t)(cid * 2 + 0) * NP + p) * 64;
      float* b2 = ws + OFF_SLAB + ((size_t)(cid * 2 + 1) * NP + p) * 64;
      *(float2*)(b1 + 2 * r) = make_float2(f1[0][j], f1[1][j]);
      *(float2*)(b2 + 2 * r) = make_float2(f2[0][j], f2[1][j]);
    }
  }
}

// ---------- kernel 3: finalize (reduce partials, force gather, Es) ----------
__global__ __launch_bounds__(512) void k3(const float* __restrict__ Rs,
                                          const float* __restrict__ ws,
                                          float* __restrict__ out) {
  const int m = blockIdx.x;
  const int tid = threadIdx.x;
  __shared__ float fx[NP];
  __shared__ float sR[NA * 3];
  __shared__ float sEsw[8], sSww[8];
  __shared__ float sTot[2];
  if (tid < NA * 3) sR[tid] = Rs[m * NA * 3 + tid];

  // Es / sw: reduce 375 per-tile partials
  float aE = 0.f, aS = 0.f;
  for (int tt = tid; tt < 375; tt += 512) {
    aE += ws[OFF_ESP + (size_t)tt * 64 + m];
    aS += ws[OFF_SWP + (size_t)tt * 64 + m];
  }
#pragma unroll
  for (int off = 32; off; off >>= 1) {
    aE += __shfl_down(aE, off);
    aS += __shfl_down(aS, off);
  }
  if ((tid & 63) == 0) { sEsw[tid >> 6] = aE; sSww[tid >> 6] = aS; }
  __syncthreads();
  if (tid == 0) {
    float e = 0.f, s = 0.f;
#pragma unroll
    for (int w = 0; w < 8; w++) { e += sEsw[w]; s += sSww[w]; }
    sTot[0] = e; sTot[1] = s;
    out[m] = e / QC;  // *STD + C, STD=1, C=0
  }
  __syncthreads();
  const float sw = sTot[1];

  for (int p = tid; p < NP; p += 512) {
    float f1p = 0.f, f2 = 0.f;
#pragma unroll
    for (int s = 0; s < G2S; s++) {
      f1p += ws[OFF_SLAB + ((size_t)(s * 2 + 0) * NP + p) * 64 + m];
      f2  += ws[OFF_SLAB + ((size_t)(s * 2 + 1) * NP + p) * 64 + m];
    }
    int i, j;
    p2ij(p, i, j);
    const float dx = sR[i * 3 + 0] - sR[j * 3 + 0];
    const float dy = sR[i * 3 + 1] - sR[j * 3 + 1];
    const float dz = sR[i * 3 + 2] - sR[j * 3 + 2];
    const float u = 1.0f / sqrtf(dx * dx + dy * dy + dz * dz);
    const float F1 = QC * (u * sw - f1p);
    fx[p] = (F1 - f2) * u * u * u;
  }
  __syncthreads();

  if (tid < NA * 3) {
    const int a = tid / 3, cc = tid % 3;
    const float ra = sR[a * 3 + cc];
    float acc = 0.f;
    for (int b = 0; b < NA; b++) {
      if (b == a) continue;
      const int i = a > b ? a : b, j = a > b ? b : a;
      const int p = i * (i - 1) / 2 + j;
      acc += (sR[b * 3 + cc] - ra) * fx[p];
    }
    out[MM + m * NA * 3 + tid] = acc;
  }
}

extern "C" void kernel_launch(void* const* d_in, const int* in_sizes, int n_in,
                              void* d_out, int out_size, void* d_ws, size_t ws_size,
                              hipStream_t stream) {
  const float* Rs = (const float*)d_in[0];
  const float* xt = (const float*)d_in[1];
  const float* Ja = (const float*)d_in[2];
  float* out = (float*)d_out;
  float* ws = (float*)d_ws;

  k1<<<dim3(375, 2), 256, 0, stream>>>(Rs, xt, Ja, ws);
  k2<<<dim3(18, G2S), 256, 0, stream>>>(xt, Ja, ws);
  k3<<<MM, 512, 0, stream>>>(Rs, ws, out);
}

// Round 2
// 129.764 us; speedup vs baseline: 1.1731x; 1.1731x over previous
//
#include <hip/hip_runtime.h>
#include <math.h>

#define MM 64
#define NA 24
#define NP 276
#define NT 6000
#define QC 0.22360679774997896f
#define EXPC 0.01666666666666667f  // 5/(3*sig^2), sig=10

// ---- workspace layout (float offsets) ----
#define OFF_WT   0           // wT[t][m] 6048*64 (rows 6000..6047 zeroed by k_pre)
#define OFF_ET   387072      // eT[t][m] 6048*64
#define OFF_SLAB 774144      // slab[cid][mat][p][m] 28*2*276*64 (k2 partials)
#define OFF_ESP  1763328     // esP[tile][m] 375*64
#define OFF_SWP  1787328     // swP[tile][m] 375*64
#define OFF_XS2  1811328     // xsT2[half][p][ml] 2*276*32
#define OFF_UU   1828992     // 64
#define OFF_VV   1829056     // 6000
#define OFF_C1   1835056     // 6000

// k2 tiles
#define G2S   28   // k-chunks (18*28 = 504 blocks = 2/CU, uniform)
#define G2CH  216  // k per chunk
#define G2R   72   // k per LDS staging round (3 rounds/chunk)
#define G2_AS 68
#define G2_BS 18

__device__ __forceinline__ void p2ij(int p, int& i, int& j) {
  int ii = (int)((1.0f + sqrtf(1.0f + 8.0f * (float)p)) * 0.5f);
  while (ii * (ii - 1) / 2 > p) ii--;
  while ((ii + 1) * ii / 2 <= p) ii++;
  j = p - ii * (ii - 1) / 2;
  i = ii;
}

// ---------- kernel 0: xsT2 + uu (blocks 0..63), vv/c1 stats (blocks 64..438) ----------
__global__ __launch_bounds__(256) void k_pre(const float* __restrict__ Rs,
                                             const float* __restrict__ xt,
                                             const float* __restrict__ Ja,
                                             float* __restrict__ ws) {
  const int tid = threadIdx.x;
  const int bid = blockIdx.x;
  if (bid < MM) {
    // blocks 0,1 also zero the wT/eT tail rows (6000..6047)
    if (bid < 2) {
      float* tz = ws + (bid ? OFF_ET : OFF_WT) + (size_t)NT * 64;
      for (int z = tid; z < 48 * 64; z += 256) tz[z] = 0.f;
    }
    const int m = bid;
    __shared__ float sR[NA * 3];
    __shared__ float sAcc[4];
    if (tid < NA * 3) sR[tid] = Rs[m * NA * 3 + tid];
    __syncthreads();
    float acc = 0.f;
    for (int p = tid; p < NP; p += 256) {
      int i, j;
      p2ij(p, i, j);
      const float dx = sR[i * 3 + 0] - sR[j * 3 + 0];
      const float dy = sR[i * 3 + 1] - sR[j * 3 + 1];
      const float dz = sR[i * 3 + 2] - sR[j * 3 + 2];
      const float u = 1.0f / sqrtf(dx * dx + dy * dy + dz * dz);
      ws[OFF_XS2 + (size_t)(m >> 5) * NP * 32 + p * 32 + (m & 31)] = u;
      acc = fmaf(u, u, acc);
    }
#pragma unroll
    for (int off = 32; off; off >>= 1) acc += __shfl_down(acc, off);
    if ((tid & 63) == 0) sAcc[tid >> 6] = acc;
    __syncthreads();
    if (tid == 0) ws[OFF_UU + m] = sAcc[0] + sAcc[1] + sAcc[2] + sAcc[3];
  } else {
    // stats: vv[t] = sum_k xt[t][k]^2, c1[t] = sum_k xt[t][k]*Ja[t][k]
    const int tl = tid >> 4;
    const int l16 = tid & 15;
    const int t = (bid - MM) * 16 + tl;
    const float* xr = xt + (size_t)t * NP;
    const float* jr = Ja + (size_t)t * NP;
    float a = 0.f, b = 0.f;
#pragma unroll 4
    for (int k = l16; k < NP; k += 16) {
      const float v = xr[k];
      a = fmaf(v, v, a);
      b = fmaf(v, jr[k], b);
    }
#pragma unroll
    for (int off = 8; off; off >>= 1) {
      a += __shfl_down(a, off, 16);
      b += __shfl_down(b, off, 16);
    }
    if (l16 == 0) { ws[OFF_VV + t] = a; ws[OFF_C1 + t] = b; }
  }
}

// ---------- kernel 1: GEMM1 + elementwise, flat-copy staging, single pre-GEMM barrier ----------
// grid (375 t-tiles, 2 m-halves); block 256 = tile 32m x 16t.
// Thread: r = tid&15 -> m-pair (m0+2r, +1); c = tid>>4 -> t = t0+c.
__global__ __launch_bounds__(256, 2) void k1(const float* __restrict__ xt,
                                             const float* __restrict__ Ja,
                                             float* __restrict__ ws) {
  __shared__ __align__(16) float Bv[16 * NP];   // flat copy of xt tile (rows adjacent)
  __shared__ __align__(16) float Bj[16 * NP];   // flat copy of Ja tile
  __shared__ __align__(16) float As[NP * 32];   // xsT2 half, [p][ml]
  __shared__ float sEsW[4][32], sSwW[4][32];
  const int tid = threadIdx.x;
  const int t0 = blockIdx.x * 16;
  const int m0 = blockIdx.y * 32;
  const int r = tid & 15;   // m-pair
  const int c = tid >> 4;   // t-column

  // scalar per-thread params (global, independent of LDS)
  const float vvt = ws[OFF_VV + t0 + c];
  const float c1t = ws[OFF_C1 + t0 + c];
  const float2 uu2 = *(const float2*)(ws + OFF_UU + m0 + 2 * r);

  // stage: pure linear float4 copies (B tiles are 16 contiguous rows)
  {
    const float4* xs4 = (const float4*)(xt + (size_t)t0 * NP);
    const float4* js4 = (const float4*)(Ja + (size_t)t0 * NP);
    const float4* as4 = (const float4*)(ws + OFF_XS2 + (size_t)blockIdx.y * NP * 32);
    float4* bv4 = (float4*)Bv;
    float4* bj4 = (float4*)Bj;
    float4* a4  = (float4*)As;
    for (int i = tid; i < 16 * NP / 4; i += 256) { bv4[i] = xs4[i]; bj4[i] = js4[i]; }
    for (int i = tid; i < NP * 32 / 4; i += 256) a4[i] = as4[i];
  }
  __syncthreads();

  float av0 = 0.f, av1 = 0.f, aj0 = 0.f, aj1 = 0.f;
  const float* BvR = Bv + c * NP;
  const float* BjR = Bj + c * NP;
  const float* Ac = As + 2 * r;
#pragma unroll 3
  for (int kk = 0; kk < NP; kk += 4) {
    const float4 bv = *(const float4*)(BvR + kk);
    const float4 bj = *(const float4*)(BjR + kk);
    const float2 a0 = *(const float2*)(Ac + (kk + 0) * 32);
    const float2 a1 = *(const float2*)(Ac + (kk + 1) * 32);
    const float2 a2 = *(const float2*)(Ac + (kk + 2) * 32);
    const float2 a3 = *(const float2*)(Ac + (kk + 3) * 32);
    av0 = fmaf(a0.x, bv.x, av0); aj0 = fmaf(a0.x, bj.x, aj0);
    av1 = fmaf(a0.y, bv.x, av1); aj1 = fmaf(a0.y, bj.x, aj1);
    av0 = fmaf(a1.x, bv.y, av0); aj0 = fmaf(a1.x, bj.y, aj0);
    av1 = fmaf(a1.y, bv.y, av1); aj1 = fmaf(a1.y, bj.y, aj1);
    av0 = fmaf(a2.x, bv.z, av0); aj0 = fmaf(a2.x, bj.z, aj0);
    av1 = fmaf(a2.y, bv.z, av1); aj1 = fmaf(a2.y, bj.z, aj1);
    av0 = fmaf(a3.x, bv.w, av0); aj0 = fmaf(a3.x, bj.w, aj0);
    av1 = fmaf(a3.y, bv.w, av1); aj1 = fmaf(a3.y, bj.w, aj1);
  }

  // elementwise epilogue: t = t0+c, m = m0+2r+{0,1}
  float es2[2], sw2[2], wv[2], ev[2];
#pragma unroll
  for (int i = 0; i < 2; i++) {
    const float g1v = i ? av1 : av0;
    const float g2v = i ? aj1 : aj0;
    const float uum = i ? uu2.y : uu2.x;
    float d2 = fmaxf(uum - 2.f * g1v + vvt, 0.f);
    float xd = QC * sqrtf(d2);
    float dv = QC * (g2v - c1t);
    float ex = EXPC * __expf(-xd);
    float e1v = ex * (1.f + xd);
    float w_ = ex * dv;
    wv[i] = w_; ev[i] = e1v;
    es2[i] = e1v * dv;
    sw2[i] = w_;
  }
  const int t = t0 + c;
  *(float2*)(ws + OFF_WT + (size_t)t * 64 + m0 + 2 * r) = make_float2(wv[0], wv[1]);
  *(float2*)(ws + OFF_ET + (size_t)t * 64 + m0 + 2 * r) = make_float2(ev[0], ev[1]);

  // reduce es/sw over the wave's 4 c-groups, park per wave, plain stores
#pragma unroll
  for (int i = 0; i < 2; i++) {
    es2[i] += __shfl_down(es2[i], 32); es2[i] += __shfl_down(es2[i], 16);
    sw2[i] += __shfl_down(sw2[i], 32); sw2[i] += __shfl_down(sw2[i], 16);
  }
  const int w = tid >> 6;
  if ((tid & 63) < 16) {
    sEsW[w][2 * r + 0] = es2[0]; sEsW[w][2 * r + 1] = es2[1];
    sSwW[w][2 * r + 0] = sw2[0]; sSwW[w][2 * r + 1] = sw2[1];
  }
  __syncthreads();
  if (tid < 32) {
    const float es = sEsW[0][tid] + sEsW[1][tid] + sEsW[2][tid] + sEsW[3][tid];
    const float sw = sSwW[0][tid] + sSwW[1][tid] + sSwW[2][tid] + sSwW[3][tid];
    ws[OFF_ESP + (size_t)blockIdx.x * 64 + m0 + tid] = es;
    ws[OFF_SWP + (size_t)blockIdx.x * 64 + m0 + tid] = sw;
  }
}

// ---------- kernel 2: GEMM2 partials, no atomics ----------
// grid (18 p-tiles x 28 k-chunks of 216); block 256 = tile 64m x 16p.
__global__ __launch_bounds__(256, 2) void k2(const float* __restrict__ xt,
                                             const float* __restrict__ Ja,
                                             float* __restrict__ ws) {
  __shared__ __align__(16) float Aw[G2R][G2_AS];
  __shared__ __align__(16) float Ae[G2R][G2_AS];
  __shared__ __align__(16) float2 Bvj[G2R][G2_BS];
  const int tid = threadIdx.x;
  const int p0 = blockIdx.x * 16;
  const int cid = blockIdx.y;
  const int validp = (NP - p0 < 16) ? (NP - p0) : 16;
  const int r = tid & 31;
  const int c = tid >> 5;
  float f1[2][2] = {{0.f, 0.f}, {0.f, 0.f}};  // [m][p]
  float f2[2][2] = {{0.f, 0.f}, {0.f, 0.f}};

  for (int rnd = 0; rnd < 3; rnd++) {
    const int k0 = cid * G2CH + rnd * G2R;
    __syncthreads();
    for (int idx = tid; idx < G2R * 16; idx += 256) {
      const int k = idx >> 4;
      const int mq = (idx & 15) * 4;
      *(float4*)&Aw[k][mq] = *(const float4*)(ws + OFF_WT + (size_t)(k0 + k) * 64 + mq);
      *(float4*)&Ae[k][mq] = *(const float4*)(ws + OFF_ET + (size_t)(k0 + k) * 64 + mq);
    }
    for (int idx = tid; idx < G2R * 4; idx += 256) {
      const int k = idx >> 2;
      const int pq = (idx & 3) * 4;
      const int t = k0 + k;
      float4 v = make_float4(0.f, 0.f, 0.f, 0.f), j = v;
      if (pq < validp && t < NT) {
        v = *(const float4*)(xt + (size_t)t * NP + p0 + pq);
        j = *(const float4*)(Ja + (size_t)t * NP + p0 + pq);
      }
      *(float4*)&Bvj[k][pq]     = make_float4(v.x, j.x, v.y, j.y);
      *(float4*)&Bvj[k][pq + 2] = make_float4(v.z, j.z, v.w, j.w);
    }
    __syncthreads();
#pragma unroll 4
    for (int k = 0; k < G2R; k++) {
      const float2 aw = *(const float2*)&Aw[k][2 * r];
      const float2 ae = *(const float2*)&Ae[k][2 * r];
      const float4 b  = *(const float4*)&Bvj[k][2 * c];  // (v_p, j_p, v_p1, j_p1)
      f1[0][0] = fmaf(aw.x, b.x, f1[0][0]); f1[0][1] = fmaf(aw.x, b.z, f1[0][1]);
      f1[1][0] = fmaf(aw.y, b.x, f1[1][0]); f1[1][1] = fmaf(aw.y, b.z, f1[1][1]);
      f2[0][0] = fmaf(ae.x, b.y, f2[0][0]); f2[0][1] = fmaf(ae.x, b.w, f2[0][1]);
      f2[1][0] = fmaf(ae.y, b.y, f2[1][0]); f2[1][1] = fmaf(ae.y, b.w, f2[1][1]);
    }
  }

#pragma unroll
  for (int j = 0; j < 2; j++) {
    const int pl = 2 * c + j;
    if (pl < validp) {
      const int p = p0 + pl;
      float* b1 = ws + OFF_SLAB + ((size_t)(cid * 2 + 0) * NP + p) * 64;
      float* b2 = ws + OFF_SLAB + ((size_t)(cid * 2 + 1) * NP + p) * 64;
      *(float2*)(b1 + 2 * r) = make_float2(f1[0][j], f1[1][j]);
      *(float2*)(b2 + 2 * r) = make_float2(f2[0][j], f2[1][j]);
    }
  }
}

// ---------- kernel 3: finalize (reduce partials, force gather, Es) ----------
__global__ __launch_bounds__(512) void k3(const float* __restrict__ Rs,
                                          const float* __restrict__ ws,
                                          float* __restrict__ out) {
  const int m = blockIdx.x;
  const int tid = threadIdx.x;
  __shared__ float fx[NP];
  __shared__ float sR[NA * 3];
  __shared__ float sEsw[8], sSww[8];
  __shared__ float sTot[2];
  if (tid < NA * 3) sR[tid] = Rs[m * NA * 3 + tid];

  // Es / sw: reduce 375 per-tile partials
  float aE = 0.f, aS = 0.f;
  for (int tt = tid; tt < 375; tt += 512) {
    aE += ws[OFF_ESP + (size_t)tt * 64 + m];
    aS += ws[OFF_SWP + (size_t)tt * 64 + m];
  }
#pragma unroll
  for (int off = 32; off; off >>= 1) {
    aE += __shfl_down(aE, off);
    aS += __shfl_down(aS, off);
  }
  if ((tid & 63) == 0) { sEsw[tid >> 6] = aE; sSww[tid >> 6] = aS; }
  __syncthreads();
  if (tid == 0) {
    float e = 0.f, s = 0.f;
#pragma unroll
    for (int w = 0; w < 8; w++) { e += sEsw[w]; s += sSww[w]; }
    sTot[0] = e; sTot[1] = s;
    out[m] = e / QC;  // *STD + C, STD=1, C=0
  }
  __syncthreads();
  const float sw = sTot[1];

  for (int p = tid; p < NP; p += 512) {
    float f1p = 0.f, f2 = 0.f;
#pragma unroll
    for (int s = 0; s < G2S; s++) {
      f1p += ws[OFF_SLAB + ((size_t)(s * 2 + 0) * NP + p) * 64 + m];
      f2  += ws[OFF_SLAB + ((size_t)(s * 2 + 1) * NP + p) * 64 + m];
    }
    const float u = ws[OFF_XS2 + (size_t)(m >> 5) * NP * 32 + p * 32 + (m & 31)];
    const float F1 = QC * (u * sw - f1p);
    fx[p] = (F1 - f2) * u * u * u;
  }
  __syncthreads();

  if (tid < NA * 3) {
    const int a = tid / 3, cc = tid % 3;
    const float ra = sR[a * 3 + cc];
    float acc = 0.f;
    for (int b = 0; b < NA; b++) {
      if (b == a) continue;
      const int i = a > b ? a : b, j = a > b ? b : a;
      const int p = i * (i - 1) / 2 + j;
      acc += (sR[b * 3 + cc] - ra) * fx[p];
    }
    out[MM + m * NA * 3 + tid] = acc;
  }
}

extern "C" void kernel_launch(void* const* d_in, const int* in_sizes, int n_in,
                              void* d_out, int out_size, void* d_ws, size_t ws_size,
                              hipStream_t stream) {
  const float* Rs = (const float*)d_in[0];
  const float* xt = (const float*)d_in[1];
  const float* Ja = (const float*)d_in[2];
  float* out = (float*)d_out;
  float* ws = (float*)d_ws;

  k_pre<<<MM + 375, 256, 0, stream>>>(Rs, xt, Ja, ws);
  k1<<<dim3(375, 2), 256, 0, stream>>>(xt, Ja, ws);
  k2<<<dim3(18, G2S), 256, 0, stream>>>(xt, Ja, ws);
  k3<<<MM, 512, 0, stream>>>(Rs, ws, out);
}

// Round 3
// 118.178 us; speedup vs baseline: 1.2881x; 1.0980x over previous
//
#include <hip/hip_runtime.h>
#include <math.h>

#define MM 64
#define NA 24
#define NP 276
#define NT 6000
#define QC 0.22360679774997896f
#define EXPC 0.01666666666666667f  // 5/(3*sig^2), sig=10

// k2 tiles: 6048 = 56 chunks x 108 k, single staging round per block
#define G2S   56
#define G2R   108

// ---- workspace layout (float offsets) ----
#define OFF_WT   0           // wT[t][m] 6048*64 (rows 6000..6047 zeroed by k_pre)
#define OFF_ET   387072      // eT[t][m] 6048*64
#define OFF_SLAB 774144      // slab[cid][mat][p][m] 56*2*276*64 (k2 partials)
#define OFF_ESP  2752512     // esP[tile][m] 375*64
#define OFF_SWP  2776512     // swP[tile][m] 375*64
#define OFF_XS2  2800512     // xsT2[half][p][ml] 2*276*32
#define OFF_UU   2818176     // 64
#define OFF_VV   2818240     // 6000
#define OFF_C1   2824240     // 6000
#define OFF_F    2830240     // F[mat][p][m] 2*276*64 (k_red output)
#define SLABSTRIDE 35328     // 2*276*64

__device__ __forceinline__ void p2ij(int p, int& i, int& j) {
  int ii = (int)((1.0f + sqrtf(1.0f + 8.0f * (float)p)) * 0.5f);
  while (ii * (ii - 1) / 2 > p) ii--;
  while ((ii + 1) * ii / 2 <= p) ii++;
  j = p - ii * (ii - 1) / 2;
  i = ii;
}

// ---------- kernel 0: xsT2 + uu (blocks 0..63), vv/c1 stats (blocks 64..1563) ----------
// stats blocks: 4 t-rows x 64 lanes, lane-contiguous (coalesced) reads.
__global__ __launch_bounds__(256) void k_pre(const float* __restrict__ Rs,
                                             const float* __restrict__ xt,
                                             const float* __restrict__ Ja,
                                             float* __restrict__ ws) {
  const int tid = threadIdx.x;
  const int bid = blockIdx.x;
  if (bid < MM) {
    // blocks 0,1 also zero the wT/eT tail rows (6000..6047)
    if (bid < 2) {
      float* tz = ws + (bid ? OFF_ET : OFF_WT) + (size_t)NT * 64;
      for (int z = tid; z < 48 * 64; z += 256) tz[z] = 0.f;
    }
    const int m = bid;
    __shared__ float sR[NA * 3];
    __shared__ float sAcc[4];
    if (tid < NA * 3) sR[tid] = Rs[m * NA * 3 + tid];
    __syncthreads();
    float acc = 0.f;
    for (int p = tid; p < NP; p += 256) {
      int i, j;
      p2ij(p, i, j);
      const float dx = sR[i * 3 + 0] - sR[j * 3 + 0];
      const float dy = sR[i * 3 + 1] - sR[j * 3 + 1];
      const float dz = sR[i * 3 + 2] - sR[j * 3 + 2];
      const float u = 1.0f / sqrtf(dx * dx + dy * dy + dz * dz);
      ws[OFF_XS2 + (size_t)(m >> 5) * NP * 32 + p * 32 + (m & 31)] = u;
      acc = fmaf(u, u, acc);
    }
#pragma unroll
    for (int off = 32; off; off >>= 1) acc += __shfl_down(acc, off);
    if ((tid & 63) == 0) sAcc[tid >> 6] = acc;
    __syncthreads();
    if (tid == 0) ws[OFF_UU + m] = sAcc[0] + sAcc[1] + sAcc[2] + sAcc[3];
  } else {
    // stats: vv[t] = sum_k xt[t][k]^2, c1[t] = sum_k xt[t][k]*Ja[t][k]
    const int sb = bid - MM;                 // 0..1499
    const int t = sb * 4 + (tid >> 6);       // 4 t-rows per block
    const int lane = tid & 63;
    const float* xr = xt + (size_t)t * NP;
    const float* jr = Ja + (size_t)t * NP;
    float a = 0.f, b = 0.f;
#pragma unroll
    for (int q = 0; q < 4; q++) {
      const float v = xr[lane + 64 * q];
      const float jj = jr[lane + 64 * q];
      a = fmaf(v, v, a);
      b = fmaf(v, jj, b);
    }
    if (lane < NP - 256) {
      const float v = xr[256 + lane];
      const float jj = jr[256 + lane];
      a = fmaf(v, v, a);
      b = fmaf(v, jj, b);
    }
#pragma unroll
    for (int off = 32; off; off >>= 1) {
      a += __shfl_down(a, off);
      b += __shfl_down(b, off);
    }
    if (lane == 0) { ws[OFF_VV + t] = a; ws[OFF_C1 + t] = b; }
  }
}

// ---------- kernel 1: GEMM1 + elementwise, flat-copy staging, single pre-GEMM barrier ----------
// grid (375 t-tiles, 2 m-halves); block 256 = tile 32m x 16t.
__global__ __launch_bounds__(256, 2) void k1(const float* __restrict__ xt,
                                             const float* __restrict__ Ja,
                                             float* __restrict__ ws) {
  __shared__ __align__(16) float Bv[16 * NP];   // flat copy of xt tile
  __shared__ __align__(16) float Bj[16 * NP];   // flat copy of Ja tile
  __shared__ __align__(16) float As[NP * 32];   // xsT2 half, [p][ml]
  __shared__ float sEsW[4][32], sSwW[4][32];
  const int tid = threadIdx.x;
  const int t0 = blockIdx.x * 16;
  const int m0 = blockIdx.y * 32;
  const int r = tid & 15;   // m-pair
  const int c = tid >> 4;   // t-column

  const float vvt = ws[OFF_VV + t0 + c];
  const float c1t = ws[OFF_C1 + t0 + c];
  const float2 uu2 = *(const float2*)(ws + OFF_UU + m0 + 2 * r);

  {
    const float4* xs4 = (const float4*)(xt + (size_t)t0 * NP);
    const float4* js4 = (const float4*)(Ja + (size_t)t0 * NP);
    const float4* as4 = (const float4*)(ws + OFF_XS2 + (size_t)blockIdx.y * NP * 32);
    float4* bv4 = (float4*)Bv;
    float4* bj4 = (float4*)Bj;
    float4* a4  = (float4*)As;
    for (int i = tid; i < 16 * NP / 4; i += 256) { bv4[i] = xs4[i]; bj4[i] = js4[i]; }
    for (int i = tid; i < NP * 32 / 4; i += 256) a4[i] = as4[i];
  }
  __syncthreads();

  float av0 = 0.f, av1 = 0.f, aj0 = 0.f, aj1 = 0.f;
  const float* BvR = Bv + c * NP;
  const float* BjR = Bj + c * NP;
  const float* Ac = As + 2 * r;
#pragma unroll 3
  for (int kk = 0; kk < NP; kk += 4) {
    const float4 bv = *(const float4*)(BvR + kk);
    const float4 bj = *(const float4*)(BjR + kk);
    const float2 a0 = *(const float2*)(Ac + (kk + 0) * 32);
    const float2 a1 = *(const float2*)(Ac + (kk + 1) * 32);
    const float2 a2 = *(const float2*)(Ac + (kk + 2) * 32);
    const float2 a3 = *(const float2*)(Ac + (kk + 3) * 32);
    av0 = fmaf(a0.x, bv.x, av0); aj0 = fmaf(a0.x, bj.x, aj0);
    av1 = fmaf(a0.y, bv.x, av1); aj1 = fmaf(a0.y, bj.x, aj1);
    av0 = fmaf(a1.x, bv.y, av0); aj0 = fmaf(a1.x, bj.y, aj0);
    av1 = fmaf(a1.y, bv.y, av1); aj1 = fmaf(a1.y, bj.y, aj1);
    av0 = fmaf(a2.x, bv.z, av0); aj0 = fmaf(a2.x, bj.z, aj0);
    av1 = fmaf(a2.y, bv.z, av1); aj1 = fmaf(a2.y, bj.z, aj1);
    av0 = fmaf(a3.x, bv.w, av0); aj0 = fmaf(a3.x, bj.w, aj0);
    av1 = fmaf(a3.y, bv.w, av1); aj1 = fmaf(a3.y, bj.w, aj1);
  }

  float es2[2], sw2[2], wv[2], ev[2];
#pragma unroll
  for (int i = 0; i < 2; i++) {
    const float g1v = i ? av1 : av0;
    const float g2v = i ? aj1 : aj0;
    const float uum = i ? uu2.y : uu2.x;
    float d2 = fmaxf(uum - 2.f * g1v + vvt, 0.f);
    float xd = QC * sqrtf(d2);
    float dv = QC * (g2v - c1t);
    float ex = EXPC * __expf(-xd);
    float e1v = ex * (1.f + xd);
    float w_ = ex * dv;
    wv[i] = w_; ev[i] = e1v;
    es2[i] = e1v * dv;
    sw2[i] = w_;
  }
  const int t = t0 + c;
  *(float2*)(ws + OFF_WT + (size_t)t * 64 + m0 + 2 * r) = make_float2(wv[0], wv[1]);
  *(float2*)(ws + OFF_ET + (size_t)t * 64 + m0 + 2 * r) = make_float2(ev[0], ev[1]);

#pragma unroll
  for (int i = 0; i < 2; i++) {
    es2[i] += __shfl_down(es2[i], 32); es2[i] += __shfl_down(es2[i], 16);
    sw2[i] += __shfl_down(sw2[i], 32); sw2[i] += __shfl_down(sw2[i], 16);
  }
  const int w = tid >> 6;
  if ((tid & 63) < 16) {
    sEsW[w][2 * r + 0] = es2[0]; sEsW[w][2 * r + 1] = es2[1];
    sSwW[w][2 * r + 0] = sw2[0]; sSwW[w][2 * r + 1] = sw2[1];
  }
  __syncthreads();
  if (tid < 32) {
    const float es = sEsW[0][tid] + sEsW[1][tid] + sEsW[2][tid] + sEsW[3][tid];
    const float sw = sSwW[0][tid] + sSwW[1][tid] + sSwW[2][tid] + sSwW[3][tid];
    ws[OFF_ESP + (size_t)blockIdx.x * 64 + m0 + tid] = es;
    ws[OFF_SWP + (size_t)blockIdx.x * 64 + m0 + tid] = sw;
  }
}

// ---------- kernel 2: GEMM2 partials, single 108-k staging round, no atomics ----------
// grid (18 p-tiles x 56 k-chunks); block 256 = tile 64m x 16p.
// Thread: r = tid&31 -> m-pair (2r, 2r+1); c = tid>>5 -> p-pair (p0+2c, +1).
__global__ __launch_bounds__(256, 2) void k2(const float* __restrict__ xt,
                                             const float* __restrict__ Ja,
                                             float* __restrict__ ws) {
  __shared__ __align__(16) float Aw[G2R * 64];   // flat [k][64]
  __shared__ __align__(16) float Ae[G2R * 64];
  __shared__ __align__(16) float2 Bvj[G2R][18];
  const int tid = threadIdx.x;
  const int p0 = blockIdx.x * 16;
  const int cid = blockIdx.y;
  const int k0 = cid * G2R;
  const int validp = (NP - p0 < 16) ? (NP - p0) : 16;
  const int r = tid & 31;
  const int c = tid >> 5;

  // stage A: contiguous memcpy of wT/eT rows k0..k0+107 (tail rows pre-zeroed)
  {
    const float4* aws = (const float4*)(ws + OFF_WT + (size_t)k0 * 64);
    const float4* aes = (const float4*)(ws + OFF_ET + (size_t)k0 * 64);
    float4* aw4 = (float4*)Aw;
    float4* ae4 = (float4*)Ae;
    for (int idx = tid; idx < G2R * 16; idx += 256) { aw4[idx] = aws[idx]; ae4[idx] = aes[idx]; }
  }
  // stage B: (xt,Ja) interleaved [k][p-local]
  for (int idx = tid; idx < G2R * 4; idx += 256) {
    const int k = idx >> 2;
    const int pq = (idx & 3) * 4;
    const int t = k0 + k;
    float4 v = make_float4(0.f, 0.f, 0.f, 0.f), j = v;
    if (pq < validp && t < NT) {
      v = *(const float4*)(xt + (size_t)t * NP + p0 + pq);
      j = *(const float4*)(Ja + (size_t)t * NP + p0 + pq);
    }
    *(float4*)&Bvj[k][pq]     = make_float4(v.x, j.x, v.y, j.y);
    *(float4*)&Bvj[k][pq + 2] = make_float4(v.z, j.z, v.w, j.w);
  }
  __syncthreads();

  float f1[2][2] = {{0.f, 0.f}, {0.f, 0.f}};  // [m][p]
  float f2[2][2] = {{0.f, 0.f}, {0.f, 0.f}};
#pragma unroll 4
  for (int k = 0; k < G2R; k++) {
    const float2 aw = *(const float2*)&Aw[k * 64 + 2 * r];
    const float2 ae = *(const float2*)&Ae[k * 64 + 2 * r];
    const float4 b  = *(const float4*)&Bvj[k][2 * c];  // (v_p, j_p, v_p1, j_p1)
    f1[0][0] = fmaf(aw.x, b.x, f1[0][0]); f1[0][1] = fmaf(aw.x, b.z, f1[0][1]);
    f1[1][0] = fmaf(aw.y, b.x, f1[1][0]); f1[1][1] = fmaf(aw.y, b.z, f1[1][1]);
    f2[0][0] = fmaf(ae.x, b.y, f2[0][0]); f2[0][1] = fmaf(ae.x, b.w, f2[0][1]);
    f2[1][0] = fmaf(ae.y, b.y, f2[1][0]); f2[1][1] = fmaf(ae.y, b.w, f2[1][1]);
  }

#pragma unroll
  for (int j = 0; j < 2; j++) {
    const int pl = 2 * c + j;
    if (pl < validp) {
      const int p = p0 + pl;
      float* b1 = ws + OFF_SLAB + ((size_t)(cid * 2 + 0) * NP + p) * 64;
      float* b2 = ws + OFF_SLAB + ((size_t)(cid * 2 + 1) * NP + p) * 64;
      *(float2*)(b1 + 2 * r) = make_float2(f1[0][j], f1[1][j]);
      *(float2*)(b2 + 2 * r) = make_float2(f2[0][j], f2[1][j]);
    }
  }
}

// ---------- kernel 2.5: slab reduce, fully coalesced, thread-per-output ----------
// grid (276 x 128): inner = bid*128+tid indexes [mat][p][m]; sum 56 chunks.
__global__ __launch_bounds__(128) void k_red(float* __restrict__ ws) {
  const int inner = blockIdx.x * 128 + threadIdx.x;   // < 35328 exactly
  const float* src = ws + OFF_SLAB + inner;
  float s = 0.f;
#pragma unroll
  for (int cid = 0; cid < G2S; cid++) s += src[(size_t)cid * SLABSTRIDE];
  ws[OFF_F + inner] = s;
}

// ---------- kernel 3: finalize (Es, forces) ----------
__global__ __launch_bounds__(320) void k3(const float* __restrict__ Rs,
                                          const float* __restrict__ ws,
                                          float* __restrict__ out) {
  const int m = blockIdx.x;
  const int tid = threadIdx.x;
  __shared__ float fx[NP];
  __shared__ float sR[NA * 3];
  __shared__ float sEsw[5], sSww[5];
  __shared__ float sTot[2];
  if (tid < NA * 3) sR[tid] = Rs[m * NA * 3 + tid];

  // Es / sw: reduce 375 per-tile partials
  float aE = 0.f, aS = 0.f;
  for (int tt = tid; tt < 375; tt += 320) {
    aE += ws[OFF_ESP + (size_t)tt * 64 + m];
    aS += ws[OFF_SWP + (size_t)tt * 64 + m];
  }
#pragma unroll
  for (int off = 32; off; off >>= 1) {
    aE += __shfl_down(aE, off);
    aS += __shfl_down(aS, off);
  }
  if ((tid & 63) == 0) { sEsw[tid >> 6] = aE; sSww[tid >> 6] = aS; }
  __syncthreads();
  if (tid == 0) {
    float e = 0.f, s = 0.f;
#pragma unroll
    for (int w = 0; w < 5; w++) { e += sEsw[w]; s += sSww[w]; }
    sTot[0] = e; sTot[1] = s;
    out[m] = e / QC;  // *STD + C, STD=1, C=0
  }
  __syncthreads();
  const float sw = sTot[1];

  for (int p = tid; p < NP; p += 320) {
    const float f1p = ws[OFF_F + (size_t)0 * NP * 64 + p * 64 + m];
    const float f2  = ws[OFF_F + (size_t)1 * NP * 64 + p * 64 + m];
    const float u = ws[OFF_XS2 + (size_t)(m >> 5) * NP * 32 + p * 32 + (m & 31)];
    const float F1 = QC * (u * sw - f1p);
    fx[p] = (F1 - f2) * u * u * u;
  }
  __syncthreads();

  if (tid < NA * 3) {
    const int a = tid / 3, cc = tid % 3;
    const float ra = sR[a * 3 + cc];
    float acc = 0.f;
    for (int b = 0; b < NA; b++) {
      if (b == a) continue;
      const int i = a > b ? a : b, j = a > b ? b : a;
      const int p = i * (i - 1) / 2 + j;
      acc += (sR[b * 3 + cc] - ra) * fx[p];
    }
    out[MM + m * NA * 3 + tid] = acc;
  }
}

extern "C" void kernel_launch(void* const* d_in, const int* in_sizes, int n_in,
                              void* d_out, int out_size, void* d_ws, size_t ws_size,
                              hipStream_t stream) {
  const float* Rs = (const float*)d_in[0];
  const float* xt = (const float*)d_in[1];
  const float* Ja = (const float*)d_in[2];
  float* out = (float*)d_out;
  float* ws = (float*)d_ws;

  k_pre<<<MM + 1500, 256, 0, stream>>>(Rs, xt, Ja, ws);
  k1<<<dim3(375, 2), 256, 0, stream>>>(xt, Ja, ws);
  k2<<<dim3(18, G2S), 256, 0, stream>>>(xt, Ja, ws);
  k_red<<<NP * 2, 128, 0, stream>>>(ws);
  k3<<<MM, 320, 0, stream>>>(Rs, ws, out);
}

// Round 4
// 115.281 us; speedup vs baseline: 1.3205x; 1.0251x over previous
//
#include <hip/hip_runtime.h>
#include <math.h>

#define MM 64
#define NA 24
#define NP 276
#define NT 6000
#define QC 0.22360679774997896f
#define EXPC 0.01666666666666667f  // 5/(3*sig^2), sig=10

// k2 tiles: 6048 = 56 chunks x 108 k, single staging round per block
#define G2S   56
#define G2R   108

// ---- workspace layout (float offsets) ----
#define OFF_WT   0           // wT[t][m] 6048*64 (rows 6000..6047 zeroed by k_pre)
#define OFF_ET   387072      // eT[t][m] 6048*64
#define OFF_SLAB 774144      // slab[cid][mat][p][m] 56*2*276*64 (k2 partials)
#define OFF_ESP  2752512     // esP[tile][m] 375*64
#define OFF_SWP  2776512     // swP[tile][m] 375*64
#define OFF_XS2  2800512     // xsT2[half][p][ml] 2*276*32
#define OFF_UU   2818176     // 64
#define OFF_VV   2818240     // 6000
#define OFF_C1   2824240     // 6000
#define OFF_F    2830240     // F[mat][p][m] 2*276*64 (k_red output)
#define SLABSTRIDE 35328     // 2*276*64

__device__ __forceinline__ void p2ij(int p, int& i, int& j) {
  int ii = (int)((1.0f + sqrtf(1.0f + 8.0f * (float)p)) * 0.5f);
  while (ii * (ii - 1) / 2 > p) ii--;
  while ((ii + 1) * ii / 2 <= p) ii++;
  j = p - ii * (ii - 1) / 2;
  i = ii;
}

// ---------- kernel 0: xsT2 + uu (blocks 0..63), vv/c1 stats (blocks 64..1563) ----------
__global__ __launch_bounds__(256) void k_pre(const float* __restrict__ Rs,
                                             const float* __restrict__ xt,
                                             const float* __restrict__ Ja,
                                             float* __restrict__ ws) {
  const int tid = threadIdx.x;
  const int bid = blockIdx.x;
  if (bid < MM) {
    if (bid < 2) {
      float* tz = ws + (bid ? OFF_ET : OFF_WT) + (size_t)NT * 64;
      for (int z = tid; z < 48 * 64; z += 256) tz[z] = 0.f;
    }
    const int m = bid;
    __shared__ float sR[NA * 3];
    __shared__ float sAcc[4];
    if (tid < NA * 3) sR[tid] = Rs[m * NA * 3 + tid];
    __syncthreads();
    float acc = 0.f;
    for (int p = tid; p < NP; p += 256) {
      int i, j;
      p2ij(p, i, j);
      const float dx = sR[i * 3 + 0] - sR[j * 3 + 0];
      const float dy = sR[i * 3 + 1] - sR[j * 3 + 1];
      const float dz = sR[i * 3 + 2] - sR[j * 3 + 2];
      const float u = 1.0f / sqrtf(dx * dx + dy * dy + dz * dz);
      ws[OFF_XS2 + (size_t)(m >> 5) * NP * 32 + p * 32 + (m & 31)] = u;
      acc = fmaf(u, u, acc);
    }
#pragma unroll
    for (int off = 32; off; off >>= 1) acc += __shfl_down(acc, off);
    if ((tid & 63) == 0) sAcc[tid >> 6] = acc;
    __syncthreads();
    if (tid == 0) ws[OFF_UU + m] = sAcc[0] + sAcc[1] + sAcc[2] + sAcc[3];
  } else {
    // stats: vv[t] = sum_k xt[t][k]^2, c1[t] = sum_k xt[t][k]*Ja[t][k]
    const int sb = bid - MM;                 // 0..1499
    const int t = sb * 4 + (tid >> 6);       // 4 t-rows per block
    const int lane = tid & 63;
    const float* xr = xt + (size_t)t * NP;
    const float* jr = Ja + (size_t)t * NP;
    float a = 0.f, b = 0.f;
#pragma unroll
    for (int q = 0; q < 4; q++) {
      const float v = xr[lane + 64 * q];
      const float jj = jr[lane + 64 * q];
      a = fmaf(v, v, a);
      b = fmaf(v, jj, b);
    }
    if (lane < NP - 256) {
      const float v = xr[256 + lane];
      const float jj = jr[256 + lane];
      a = fmaf(v, v, a);
      b = fmaf(v, jj, b);
    }
#pragma unroll
    for (int off = 32; off; off >>= 1) {
      a += __shfl_down(a, off);
      b += __shfl_down(b, off);
    }
    if (lane == 0) { ws[OFF_VV + t] = a; ws[OFF_C1 + t] = b; }
  }
}

// ---------- kernel 1: GEMM1, 4-way K-split, thread tile 4m x 2t (2 B/FMA) ----------
// grid (375 t-tiles, 2 m-halves); block 256 = 4 waves.
// Wave w: k-range [68w, 68w+68) (wave 3: +72). Lane: mg=lane&7 (4m), tg=lane>>3 (2t).
// Cross-wave reduce via LDS (reusing As region), wave 0 does epilogue.
#define K1SUB(A, vb0, vb1, jb0, jb1)                                               \
  av0[0] = fmaf(A.x, vb0, av0[0]); av0[1] = fmaf(A.y, vb0, av0[1]);                \
  av0[2] = fmaf(A.z, vb0, av0[2]); av0[3] = fmaf(A.w, vb0, av0[3]);                \
  av1[0] = fmaf(A.x, vb1, av1[0]); av1[1] = fmaf(A.y, vb1, av1[1]);                \
  av1[2] = fmaf(A.z, vb1, av1[2]); av1[3] = fmaf(A.w, vb1, av1[3]);                \
  aj0[0] = fmaf(A.x, jb0, aj0[0]); aj0[1] = fmaf(A.y, jb0, aj0[1]);                \
  aj0[2] = fmaf(A.z, jb0, aj0[2]); aj0[3] = fmaf(A.w, jb0, aj0[3]);                \
  aj1[0] = fmaf(A.x, jb1, aj1[0]); aj1[1] = fmaf(A.y, jb1, aj1[1]);                \
  aj1[2] = fmaf(A.z, jb1, aj1[2]); aj1[3] = fmaf(A.w, jb1, aj1[3]);

__global__ __launch_bounds__(256, 2) void k1(const float* __restrict__ xt,
                                             const float* __restrict__ Ja,
                                             float* __restrict__ ws) {
  __shared__ __align__(16) float Bv[16 * NP];   // flat copy of xt tile
  __shared__ __align__(16) float Bj[16 * NP];   // flat copy of Ja tile
  __shared__ __align__(16) float As[NP * 32];   // xsT2 half [p][ml]; reused as red[3][16][64]
  const int tid = threadIdx.x;
  const int t0 = blockIdx.x * 16;
  const int m0 = blockIdx.y * 32;
  const int w = tid >> 6;
  const int lane = tid & 63;
  const int mg = lane & 7;     // m-quad: m = m0 + 4*mg .. +3
  const int tg = lane >> 3;    // t-pair: t = t0 + 2*tg + {0,1}

  // epilogue params (only wave 0 uses; load early for latency)
  const float4 uu4 = *(const float4*)(ws + OFF_UU + m0 + 4 * mg);
  const float2 vv2 = *(const float2*)(ws + OFF_VV + t0 + 2 * tg);
  const float2 c12 = *(const float2*)(ws + OFF_C1 + t0 + 2 * tg);

  // stage: pure linear float4 copies
  {
    const float4* xs4 = (const float4*)(xt + (size_t)t0 * NP);
    const float4* js4 = (const float4*)(Ja + (size_t)t0 * NP);
    const float4* as4 = (const float4*)(ws + OFF_XS2 + (size_t)blockIdx.y * NP * 32);
    float4* bv4 = (float4*)Bv;
    float4* bj4 = (float4*)Bj;
    float4* a4  = (float4*)As;
    for (int i = tid; i < 16 * NP / 4; i += 256) { bv4[i] = xs4[i]; bj4[i] = js4[i]; }
    for (int i = tid; i < NP * 32 / 4; i += 256) a4[i] = as4[i];
  }
  __syncthreads();

  float av0[4] = {0.f, 0.f, 0.f, 0.f}, av1[4] = {0.f, 0.f, 0.f, 0.f};
  float aj0[4] = {0.f, 0.f, 0.f, 0.f}, aj1[4] = {0.f, 0.f, 0.f, 0.f};
  const float* BvR0 = Bv + (2 * tg + 0) * NP;
  const float* BvR1 = Bv + (2 * tg + 1) * NP;
  const float* BjR0 = Bj + (2 * tg + 0) * NP;
  const float* BjR1 = Bj + (2 * tg + 1) * NP;
  const float* Ac = As + 4 * mg;
  const int kbeg = w * 68;
  const int kend = (w == 3) ? NP : (kbeg + 68);
#pragma unroll 2
  for (int k = kbeg; k < kend; k += 4) {
    const float4 a0 = *(const float4*)(Ac + (k + 0) * 32);
    const float4 a1 = *(const float4*)(Ac + (k + 1) * 32);
    const float4 a2 = *(const float4*)(Ac + (k + 2) * 32);
    const float4 a3 = *(const float4*)(Ac + (k + 3) * 32);
    const float4 bv0 = *(const float4*)(BvR0 + k);
    const float4 bv1 = *(const float4*)(BvR1 + k);
    const float4 bj0 = *(const float4*)(BjR0 + k);
    const float4 bj1 = *(const float4*)(BjR1 + k);
    K1SUB(a0, bv0.x, bv1.x, bj0.x, bj1.x)
    K1SUB(a1, bv0.y, bv1.y, bj0.y, bj1.y)
    K1SUB(a2, bv0.z, bv1.z, bj0.z, bj1.z)
    K1SUB(a3, bv0.w, bv1.w, bj0.w, bj1.w)
  }
  __syncthreads();   // all waves done reading As/Bv/Bj

  if (w > 0) {
    float* red = As + (size_t)(w - 1) * 16 * 64;
#pragma unroll
    for (int q = 0; q < 4; q++) {
      red[(q + 0) * 64 + lane]  = av0[q];
      red[(q + 4) * 64 + lane]  = av1[q];
      red[(q + 8) * 64 + lane]  = aj0[q];
      red[(q + 12) * 64 + lane] = aj1[q];
    }
  }
  __syncthreads();
  if (w == 0) {
#pragma unroll
    for (int ww = 0; ww < 3; ww++) {
      const float* red = As + (size_t)ww * 16 * 64;
#pragma unroll
      for (int q = 0; q < 4; q++) {
        av0[q] += red[(q + 0) * 64 + lane];
        av1[q] += red[(q + 4) * 64 + lane];
        aj0[q] += red[(q + 8) * 64 + lane];
        aj1[q] += red[(q + 12) * 64 + lane];
      }
    }
    float es[4] = {0.f, 0.f, 0.f, 0.f}, swv[4] = {0.f, 0.f, 0.f, 0.f};
    const float uum[4] = {uu4.x, uu4.y, uu4.z, uu4.w};
#pragma unroll
    for (int tj = 0; tj < 2; tj++) {
      const float vvt = tj ? vv2.y : vv2.x;
      const float c1t = tj ? c12.y : c12.x;
      const float* g1 = tj ? av1 : av0;
      const float* g2 = tj ? aj1 : aj0;
      float wq[4], eq[4];
#pragma unroll
      for (int mi = 0; mi < 4; mi++) {
        const float d2 = fmaxf(uum[mi] - 2.f * g1[mi] + vvt, 0.f);
        const float xd = QC * sqrtf(d2);
        const float dv = QC * (g2[mi] - c1t);
        const float ex = EXPC * __expf(-xd);
        const float e1v = ex * (1.f + xd);
        const float w_ = ex * dv;
        wq[mi] = w_; eq[mi] = e1v;
        es[mi] += e1v * dv; swv[mi] += w_;
      }
      const int t = t0 + 2 * tg + tj;
      *(float4*)(ws + OFF_WT + (size_t)t * 64 + m0 + 4 * mg) = make_float4(wq[0], wq[1], wq[2], wq[3]);
      *(float4*)(ws + OFF_ET + (size_t)t * 64 + m0 + 4 * mg) = make_float4(eq[0], eq[1], eq[2], eq[3]);
    }
    // reduce es/sw over the 8 t-groups (lane bits 3..5)
#pragma unroll
    for (int q = 0; q < 4; q++) {
      es[q] += __shfl_down(es[q], 32); es[q] += __shfl_down(es[q], 16); es[q] += __shfl_down(es[q], 8);
      swv[q] += __shfl_down(swv[q], 32); swv[q] += __shfl_down(swv[q], 16); swv[q] += __shfl_down(swv[q], 8);
    }
    if (lane < 8) {
      *(float4*)(ws + OFF_ESP + (size_t)blockIdx.x * 64 + m0 + 4 * lane) =
          make_float4(es[0], es[1], es[2], es[3]);
      *(float4*)(ws + OFF_SWP + (size_t)blockIdx.x * 64 + m0 + 4 * lane) =
          make_float4(swv[0], swv[1], swv[2], swv[3]);
    }
  }
}

// ---------- kernel 2: GEMM2, 4-way K-split, thread tile 4m x 4p (2 B/FMA) ----------
// grid (18 p-tiles x 56 k-chunks); block 256 = 4 waves.
// Wave w: k-range [27w, 27w+27). Lane: mg=lane&15 (4m), pg=lane>>4 (4p).
__global__ __launch_bounds__(256, 2) void k2(const float* __restrict__ xt,
                                             const float* __restrict__ Ja,
                                             float* __restrict__ ws) {
  __shared__ __align__(16) float Aw[G2R * 64];   // flat [k][64]; reused as red[3][32][64]
  __shared__ __align__(16) float Ae[G2R * 64];
  __shared__ __align__(16) float2 Bvj[G2R][16];  // (v,j) interleaved [k][p-local]
  const int tid = threadIdx.x;
  const int p0 = blockIdx.x * 16;
  const int cid = blockIdx.y;
  const int k0 = cid * G2R;
  const int validp = (NP - p0 < 16) ? (NP - p0) : 16;
  const int w = tid >> 6;
  const int lane = tid & 63;
  const int mg = lane & 15;   // m-quad: m = 4*mg .. +3
  const int pg = lane >> 4;   // p-quad: p = p0 + 4*pg .. +3

  // stage A: contiguous memcpy of wT/eT rows k0..k0+107 (tail rows pre-zeroed)
  {
    const float4* aws = (const float4*)(ws + OFF_WT + (size_t)k0 * 64);
    const float4* aes = (const float4*)(ws + OFF_ET + (size_t)k0 * 64);
    float4* aw4 = (float4*)Aw;
    float4* ae4 = (float4*)Ae;
    for (int idx = tid; idx < G2R * 16; idx += 256) { aw4[idx] = aws[idx]; ae4[idx] = aes[idx]; }
  }
  // stage B: (xt,Ja) interleaved [k][p-local]
  for (int idx = tid; idx < G2R * 4; idx += 256) {
    const int k = idx >> 2;
    const int pq = (idx & 3) * 4;
    const int t = k0 + k;
    float4 v = make_float4(0.f, 0.f, 0.f, 0.f), j = v;
    if (pq < validp && t < NT) {
      v = *(const float4*)(xt + (size_t)t * NP + p0 + pq);
      j = *(const float4*)(Ja + (size_t)t * NP + p0 + pq);
    }
    *(float4*)&Bvj[k][pq]     = make_float4(v.x, j.x, v.y, j.y);
    *(float4*)&Bvj[k][pq + 2] = make_float4(v.z, j.z, v.w, j.w);
  }
  __syncthreads();

  float f1[4][4] = {{0.f}}, f2[4][4] = {{0.f}};
  const float* AwL = Aw + 4 * mg;
  const float* AeL = Ae + 4 * mg;
  const int kb = w * 27;
  const int ke = kb + 27;
#pragma unroll 3
  for (int k = kb; k < ke; ++k) {
    const float4 aw = *(const float4*)(AwL + (size_t)k * 64);
    const float4 ae = *(const float4*)(AeL + (size_t)k * 64);
    const float4 b01 = *(const float4*)&Bvj[k][4 * pg];
    const float4 b23 = *(const float4*)&Bvj[k][4 * pg + 2];
    const float vb[4] = {b01.x, b01.z, b23.x, b23.z};
    const float jb[4] = {b01.y, b01.w, b23.y, b23.w};
    const float aww[4] = {aw.x, aw.y, aw.z, aw.w};
    const float aee[4] = {ae.x, ae.y, ae.z, ae.w};
#pragma unroll
    for (int mi = 0; mi < 4; mi++)
#pragma unroll
      for (int pj = 0; pj < 4; pj++) {
        f1[mi][pj] = fmaf(aww[mi], vb[pj], f1[mi][pj]);
        f2[mi][pj] = fmaf(aee[mi], jb[pj], f2[mi][pj]);
      }
  }
  __syncthreads();   // all waves done reading Aw/Ae/Bvj

  if (w > 0) {
    float* red = Aw + (size_t)(w - 1) * 32 * 64;
#pragma unroll
    for (int mi = 0; mi < 4; mi++)
#pragma unroll
      for (int pj = 0; pj < 4; pj++) {
        red[(mi * 4 + pj) * 64 + lane]        = f1[mi][pj];
        red[(16 + mi * 4 + pj) * 64 + lane]   = f2[mi][pj];
      }
  }
  __syncthreads();
  if (w == 0) {
#pragma unroll
    for (int ww = 0; ww < 3; ww++) {
      const float* red = Aw + (size_t)ww * 32 * 64;
#pragma unroll
      for (int mi = 0; mi < 4; mi++)
#pragma unroll
        for (int pj = 0; pj < 4; pj++) {
          f1[mi][pj] += red[(mi * 4 + pj) * 64 + lane];
          f2[mi][pj] += red[(16 + mi * 4 + pj) * 64 + lane];
        }
    }
    float* b1 = ws + OFF_SLAB + (size_t)(cid * 2 + 0) * NP * 64;
    float* b2 = ws + OFF_SLAB + (size_t)(cid * 2 + 1) * NP * 64;
#pragma unroll
    for (int pj = 0; pj < 4; pj++) {
      const int pl = 4 * pg + pj;
      if (pl < validp) {
        const int p = p0 + pl;
        *(float4*)(b1 + (size_t)p * 64 + 4 * mg) =
            make_float4(f1[0][pj], f1[1][pj], f1[2][pj], f1[3][pj]);
        *(float4*)(b2 + (size_t)p * 64 + 4 * mg) =
            make_float4(f2[0][pj], f2[1][pj], f2[2][pj], f2[3][pj]);
      }
    }
  }
}

// ---------- kernel 2.5: slab reduce, fully coalesced, thread-per-output ----------
__global__ __launch_bounds__(128) void k_red(float* __restrict__ ws) {
  const int inner = blockIdx.x * 128 + threadIdx.x;   // < 35328 exactly
  const float* src = ws + OFF_SLAB + inner;
  float s = 0.f;
#pragma unroll
  for (int cid = 0; cid < G2S; cid++) s += src[(size_t)cid * SLABSTRIDE];
  ws[OFF_F + inner] = s;
}

// ---------- kernel 3: finalize (Es, forces) ----------
__global__ __launch_bounds__(320) void k3(const float* __restrict__ Rs,
                                          const float* __restrict__ ws,
                                          float* __restrict__ out) {
  const int m = blockIdx.x;
  const int tid = threadIdx.x;
  __shared__ float fx[NP];
  __shared__ float sR[NA * 3];
  __shared__ float sEsw[5], sSww[5];
  __shared__ float sTot[2];
  if (tid < NA * 3) sR[tid] = Rs[m * NA * 3 + tid];

  float aE = 0.f, aS = 0.f;
  for (int tt = tid; tt < 375; tt += 320) {
    aE += ws[OFF_ESP + (size_t)tt * 64 + m];
    aS += ws[OFF_SWP + (size_t)tt * 64 + m];
  }
#pragma unroll
  for (int off = 32; off; off >>= 1) {
    aE += __shfl_down(aE, off);
    aS += __shfl_down(aS, off);
  }
  if ((tid & 63) == 0) { sEsw[tid >> 6] = aE; sSww[tid >> 6] = aS; }
  __syncthreads();
  if (tid == 0) {
    float e = 0.f, s = 0.f;
#pragma unroll
    for (int w = 0; w < 5; w++) { e += sEsw[w]; s += sSww[w]; }
    sTot[0] = e; sTot[1] = s;
    out[m] = e / QC;  // *STD + C, STD=1, C=0
  }
  __syncthreads();
  const float sw = sTot[1];

  for (int p = tid; p < NP; p += 320) {
    const float f1p = ws[OFF_F + (size_t)0 * NP * 64 + p * 64 + m];
    const float f2  = ws[OFF_F + (size_t)1 * NP * 64 + p * 64 + m];
    const float u = ws[OFF_XS2 + (size_t)(m >> 5) * NP * 32 + p * 32 + (m & 31)];
    const float F1 = QC * (u * sw - f1p);
    fx[p] = (F1 - f2) * u * u * u;
  }
  __syncthreads();

  if (tid < NA * 3) {
    const int a = tid / 3, cc = tid % 3;
    const float ra = sR[a * 3 + cc];
    float acc = 0.f;
    for (int b = 0; b < NA; b++) {
      if (b == a) continue;
      const int i = a > b ? a : b, j = a > b ? b : a;
      const int p = i * (i - 1) / 2 + j;
      acc += (sR[b * 3 + cc] - ra) * fx[p];
    }
    out[MM + m * NA * 3 + tid] = acc;
  }
}

extern "C" void kernel_launch(void* const* d_in, const int* in_sizes, int n_in,
                              void* d_out, int out_size, void* d_ws, size_t ws_size,
                              hipStream_t stream) {
  const float* Rs = (const float*)d_in[0];
  const float* xt = (const float*)d_in[1];
  const float* Ja = (const float*)d_in[2];
  float* out = (float*)d_out;
  float* ws = (float*)d_ws;

  k_pre<<<MM + 1500, 256, 0, stream>>>(Rs, xt, Ja, ws);
  k1<<<dim3(375, 2), 256, 0, stream>>>(xt, Ja, ws);
  k2<<<dim3(18, G2S), 256, 0, stream>>>(xt, Ja, ws);
  k_red<<<NP * 2, 128, 0, stream>>>(ws);
  k3<<<MM, 320, 0, stream>>>(Rs, ws, out);
}